// Round 14
// baseline (129.331 us; speedup 1.0000x reference)
//
#include <hip/hip_runtime.h>
#include <cmath>

// EmbedMaskPostProcessor: top-k select + box decode + embedding-distance masks.
// Output [2,200,384,384] f32 = 236 MB, <1% nonzero -> write-BW bound (~34us floor).
// R14 = R8 (best, 100.6us) with the output node split:
//   k_fill: pure grid-stride f4 zero of ALL 236MB — byte-identical pattern to
//           the rocclr fill that sustains 6.8-7.1 TB/s (no meta reads, no
//           branches, no co-running latency blocks).
//   k_box:  400 blocks patch in-box values over the zeros (graph edge = order).
// R13 lesson: nontemporal stores are SLOWER than plain (+23us); keep plain.

namespace {
constexpr int NIMG = 2;
constexpr int NC   = 80;
constexpr int NHW  = 96 * 96;        // 9216
constexpr int NCHW = NC * NHW;       // 737280
constexpr int NDIM = 32;
constexpr int PH = 192, PW = 192;    // pixel_embed spatial
constexpr int OH = 384, OW = 384;    // output mask spatial
constexpr int KTOP = 200;
constexpr int CAP = 4096;            // gathered band candidates per image
constexpr int MCAP = 1024;           // member cap after 27-bit refine
constexpr int LCAP = 512;            // per-block gather buffer
constexpr float PRE_THRESH = 0.05f;
constexpr unsigned KEY_ZERO = 0x80000000u;  // key of +0.0f
constexpr float IMG_MAX = 767.0f;

constexpr int NBOX = NIMG * KTOP;    // 400 box-patch blocks

constexpr int NF4 = NCHW / 4;        // 184320
constexpr int SEL_BLOCKS = 128;      // selection blocks per image (grid = 256)
constexpr int SEL_STRIDE = SEL_BLOCKS * 256;                    // 32768
constexpr int SEL_ITERS = (NF4 + SEL_STRIDE - 1) / SEL_STRIDE;  // 6

// ws layout (4-byte words); control words on separate 128B lines.
constexpr int WS_HIST1 = 0;                          // [NIMG][2048]
constexpr int WS_CNT   = 4096;                       // [NIMG]
constexpr int WS_BAR   = 4128;                       // [1] sel barrier
constexpr int WS_TICK  = 4160;                       // [NIMG]
constexpr int WS_ZERO_WORDS = 4224;
constexpr int WS_PAIRS = 4224;                       // [NIMG][CAP][2] {key,ref}
constexpr int WS_PARAMS = WS_PAIRS + NIMG * CAP * 2; // [NIMG][KTOP][40]
constexpr int PARAM_WORDS = 40;  // [0]=valid [1..4]=ix0,ix1,iy0,iy1 [5]=margin [8..39]=e

typedef float f4 __attribute__((ext_vector_type(4)));
}

__device__ __forceinline__ unsigned key_of(float f) {
  unsigned u = __float_as_uint(f);
  return (u & 0x80000000u) ? ~u : (u | 0x80000000u);  // monotone: bigger float -> bigger key
}
__device__ __forceinline__ unsigned aget(const unsigned* p) {
  return __hip_atomic_load(p, __ATOMIC_RELAXED, __HIP_MEMORY_SCOPE_AGENT);
}
__device__ __forceinline__ void aput(unsigned* p, unsigned v) {
  __hip_atomic_store(p, v, __ATOMIC_RELAXED, __HIP_MEMORY_SCOPE_AGENT);
}

__global__ __launch_bounds__(256) void k_zero_ws(unsigned* __restrict__ ws) {
  for (int j = threadIdx.x; j < WS_ZERO_WORDS; j += 256) aput(ws + j, 0u);
}

// Fused selection: keygen (keys in regs) -> hist -> spin barrier -> scan ->
// gather (LDS two-phase) -> per-image last-block exact-rank final. (R8-proven.)
__global__ __launch_bounds__(256) void k_select(
    const float* __restrict__ box_cls, const float* __restrict__ ctrness,
    const float* __restrict__ locations, const float* __restrict__ box_reg,
    const float* __restrict__ pemb, const float* __restrict__ pmar,
    unsigned* __restrict__ ws) {
  __shared__ unsigned hist[2048];
  __shared__ unsigned sh_sum[256];
  __shared__ int sh_bk[2];
  __shared__ unsigned loc[LCAP][2];
  __shared__ int lcnt;
  __shared__ unsigned gbase;
  __shared__ int sh_last;
  const int t = threadIdx.x;
  const int n = blockIdx.x >= SEL_BLOCKS;
  const int bi = blockIdx.x - n * SEL_BLOCKS;

  // ---- phase 1: keygen into registers + LDS hist (positives only) ----
  for (int i = t; i < 2048; i += 256) hist[i] = 0;
  __syncthreads();
  const float* cls = box_cls + n * NCHW;
  const float* ctr = ctrness + n * NHW;
  unsigned kk[SEL_ITERS][4];
  #pragma unroll
  for (int s = 0; s < SEL_ITERS; ++s) {
    const int j4 = s * SEL_STRIDE + bi * 256 + t;
    if (j4 < NF4) {
      const int j = j4 * 4;
      const int c = j / NHW;
      const int hw = j - c * NHW;                          // multiple of 4
      const f4 xv = *reinterpret_cast<const f4*>(cls + j);
      const f4 cv = *reinterpret_cast<const f4*>(ctr + hw);
      #pragma unroll
      for (int q = 0; q < 4; ++q) {
        const float sg = 1.0f / (1.0f + expf(-xv[q]));
        float v = -1.0f;
        if (sg > PRE_THRESH) v = sg * (1.0f / (1.0f + expf(-cv[q])));
        const unsigned k = key_of(v);
        kk[s][q] = k;
        if (k > KEY_ZERO) atomicAdd(&hist[k >> 21], 1u);
      }
    } else {
      #pragma unroll
      for (int q = 0; q < 4; ++q) kk[s][q] = 0u;
    }
  }
  __syncthreads();
  {
    unsigned* gh = ws + WS_HIST1 + n * 2048;
    for (int i = t; i < 2048; i += 256) { unsigned v = hist[i]; if (v) atomicAdd(&gh[i], v); }
  }

  // ---- spin barrier across all 256 blocks (alone on device -> harmless) ----
  __syncthreads();
  if (t == 0) {
    atomicAdd(ws + WS_BAR, 1u);
    while (aget(ws + WS_BAR) < (unsigned)(2 * SEL_BLOCKS)) __builtin_amdgcn_s_sleep(2);
  }
  __syncthreads();

  // ---- phase 2: scan global hist for b1/krem ----
  if (t == 0) { sh_bk[0] = -1; sh_bk[1] = KTOP; }
  {
    const unsigned* gh = ws + WS_HIST1 + n * 2048;
    unsigned local = 0;
    for (int j = 0; j < 8; ++j) { unsigned v = aget(gh + t * 8 + j); hist[t * 8 + j] = v; local += v; }
    sh_sum[t] = local;
  }
  __syncthreads();
  {
    unsigned S = 0;
    for (int j = t + 1; j < 256; ++j) S += sh_sum[j];
    int cand_b = -1;
    unsigned cand_above = 0;
    unsigned run = S;
    for (int j = 7; j >= 0; --j) {
      const unsigned cv = hist[t * 8 + j];
      if (cand_b < 0 && run + cv >= (unsigned)KTOP) { cand_b = t * 8 + j; cand_above = run; }
      run += cv;
    }
    if (cand_b >= 0) atomicMax(&sh_bk[0], cand_b);
    __syncthreads();
    if (cand_b >= 0 && cand_b == sh_bk[0]) sh_bk[1] = KTOP - (int)cand_above;
    __syncthreads();
  }
  const unsigned b1 = (unsigned)(sh_bk[0] < 0 ? 0 : sh_bk[0]);
  int krem = sh_bk[1];

  // ---- gather band members from registers -> LDS -> one global reservation ----
  if (t == 0) lcnt = 0;
  __syncthreads();
  #pragma unroll
  for (int s = 0; s < SEL_ITERS; ++s) {
    #pragma unroll
    for (int q = 0; q < 4; ++q) {
      const unsigned k = kk[s][q];
      if ((k >> 21) < b1) continue;
      const int j = (s * SEL_STRIDE + bi * 256 + t) * 4 + q;
      const int c = j / NHW;
      const int hw = j - c * NHW;
      const int p = atomicAdd(&lcnt, 1);
      if (p < LCAP) { loc[p][0] = k; loc[p][1] = (unsigned)(hw * NC + c); }
    }
  }
  __syncthreads();
  const int lc = min(lcnt, LCAP);
  if (t == 0) gbase = atomicAdd(ws + WS_CNT + n, (unsigned)lc);
  __syncthreads();
  for (int i = t; i < lc; i += 256) {
    const unsigned pos = gbase + (unsigned)i;
    if (pos < (unsigned)CAP) {
      aput(&ws[WS_PAIRS + (n * CAP + (int)pos) * 2], loc[i][0]);
      aput(&ws[WS_PAIRS + (n * CAP + (int)pos) * 2 + 1], loc[i][1]);
    }
  }

  // ---- per-image last-block ticket ----
  __syncthreads();
  if (t == 0) {
    const unsigned old = atomicAdd(ws + WS_TICK + n, 1u);
    sh_last = (old == (unsigned)(SEL_BLOCKS - 1)) ? 1 : 0;
  }
  __syncthreads();
  if (!sh_last) return;

  // ---- phase 3 (one block per image): refine to 27-bit prefix, compact
  //      members, exact rank (value desc, index asc = lax.top_k), emit params ----
  __shared__ uint2 P[CAP];               // 32 KiB
  __shared__ unsigned h256[256];
  __shared__ unsigned mKey[MCAP], mRef[MCAP];
  __shared__ int sh_b, sh_t;
  for (int s = t; s < KTOP; s += 256) aput(&ws[WS_PARAMS + (n * KTOP + s) * PARAM_WORDS], 0u);
  const int cnt = min((int)aget(ws + WS_CNT + n), CAP);
  for (int i = t; i < cnt; i += 256) {
    P[i].x = aget(&ws[WS_PAIRS + (n * CAP + i) * 2]);
    P[i].y = aget(&ws[WS_PAIRS + (n * CAP + i) * 2 + 1]);
  }
  __syncthreads();

  unsigned prefix = b1;
  int shift = 21;
  #pragma unroll
  for (int level = 0; level < 2; ++level) {
    const int newshift = shift - 8;
    h256[t] = 0;
    if (t == 0) sh_b = 0;
    __syncthreads();
    for (int i = t; i < cnt; i += 256) {
      const unsigned k = P[i].x;
      if ((k >> shift) == prefix) atomicAdd(&h256[(k >> newshift) & 255u], 1u);
    }
    __syncthreads();
    const unsigned hv = h256[t];
    unsigned S = 0;
    for (int j = t + 1; j < 256; ++j) S += h256[j];
    if (S + hv >= (unsigned)krem) atomicMax(&sh_b, t);
    __syncthreads();
    const int b = sh_b;
    if (t == b) sh_t = krem - (int)S;
    __syncthreads();
    krem = sh_t;
    prefix = (prefix << 8) | (unsigned)b;
    shift = newshift;
    __syncthreads();
  }

  if (t == 0) sh_t = 0;
  __syncthreads();
  for (int i = t; i < cnt; i += 256) {
    const unsigned k = P[i].x;
    if ((k >> 5) >= prefix) {
      const int pos = atomicAdd(&sh_t, 1);
      if (pos < MCAP) { mKey[pos] = k; mRef[pos] = P[i].y; }
    }
  }
  __syncthreads();
  const int m = min(sh_t, MCAP);

  for (int i = t; i < m; i += 256) {
    const unsigned ki = mKey[i], ri = mRef[i];
    int rank = 0;
    for (int j = 0; j < m; ++j) {
      const unsigned kj = mKey[j], rj = mRef[j];
      rank += (kj > ki || (kj == ki && rj < ri)) ? 1 : 0;
    }
    if (rank >= KTOP) continue;
    unsigned* pp = ws + WS_PARAMS + (n * KTOP + rank) * PARAM_WORDS;
    int valid = 0;
    if (ki > KEY_ZERO) {
      const int hw = (int)ri / NC;
      const float lx = locations[2 * hw], ly = locations[2 * hw + 1];
      const float rl = box_reg[(n * 4 + 0) * NHW + hw];
      const float rt = box_reg[(n * 4 + 1) * NHW + hw];
      const float rr = box_reg[(n * 4 + 2) * NHW + hw];
      const float rb = box_reg[(n * 4 + 3) * NHW + hw];
      const float x1 = fminf(fmaxf(lx - rl, 0.f), IMG_MAX);
      const float y1 = fminf(fmaxf(ly - rt, 0.f), IMG_MAX);
      const float x2 = fminf(fmaxf(lx + rr, 0.f), IMG_MAX);
      const float y2 = fminf(fmaxf(ly + rb, 0.f), IMG_MAX);
      const int ix0 = max(0, (int)ceilf(x1 * 0.25f));
      const int ix1 = min(OW - 1, (int)floorf(x2 * 0.25f));
      const int iy0 = max(0, (int)ceilf(y1 * 0.25f));
      const int iy1 = min(OH - 1, (int)floorf(y2 * 0.25f));
      if (ix0 <= ix1 && iy0 <= iy1) {
        valid = 1;
        aput(pp + 1, (unsigned)ix0); aput(pp + 2, (unsigned)ix1);
        aput(pp + 3, (unsigned)iy0); aput(pp + 4, (unsigned)iy1);
        aput(pp + 5, __float_as_uint(pmar[n * NHW + hw]));
        #pragma unroll
        for (int d = 0; d < NDIM; ++d)
          aput(pp + 8 + d, __float_as_uint(pemb[(n * NDIM + d) * NHW + hw]));
      }
    }
    aput(pp + 0, (unsigned)valid);
  }
}

// Pure fill clone: grid-stride plain f4 stores over the whole output.
// No meta reads, no branches — the pattern that sustains ~7 TB/s.
__global__ __launch_bounds__(256) void k_fill(f4* __restrict__ out, int n4) {
  const f4 z = {0.f, 0.f, 0.f, 0.f};
  const int stride = gridDim.x * 256;
  for (int i = blockIdx.x * 256 + threadIdx.x; i < n4; i += stride)
    out[i] = z;
}

// Box patch: one block per (n,k); writes ONLY in-box cells over the zeros
// (previous node's stores visible/ordered via the graph edge).
__global__ __launch_bounds__(256) void k_box(const float* __restrict__ pix,
                                             const unsigned* __restrict__ ws,
                                             float* __restrict__ out) {
  const int nk = blockIdx.x;
  const int t = threadIdx.x;
  const unsigned* meta = ws + WS_PARAMS + nk * PARAM_WORDS;
  if (meta[0] == 0u) return;
  const int ix0 = (int)meta[1], ix1 = (int)meta[2];
  const int iy0 = (int)meta[3], iy1 = (int)meta[4];
  const float margin = __uint_as_float(meta[5]);
  float e[NDIM];
  {
    const float4* e4 = reinterpret_cast<const float4*>(meta + 8);
    #pragma unroll
    for (int q = 0; q < NDIM / 4; ++q) {
      const float4 v = e4[q];
      e[4 * q + 0] = v.x; e[4 * q + 1] = v.y; e[4 * q + 2] = v.z; e[4 * q + 3] = v.w;
    }
  }
  const int n = nk / KTOP;
  const float* peb = pix + (size_t)n * NDIM * PH * PW;
  float* ob = out + (size_t)nk * (OH * OW);

  const int tx = t & 63;             // column lane
  const int ts = t >> 6;             // row strip 0..3
  const int h = iy1 - iy0 + 1;
  const int shh = (h + 3) >> 2;
  const int ybeg = iy0 + ts * shh;
  const int yend = min(iy0 + (ts + 1) * shh, iy1 + 1);

  for (int c = ix0 + tx; c <= ix1; c += 64) {
    const float sx = 0.5f * (float)c - 0.25f;
    const float xf = floorf(sx);
    const float fx = sx - xf;
    const int xs0 = max((int)xf, 0);
    const int xs1 = min((int)xf + 1, PW - 1);
    float qa_[NDIM], qb_[NDIM];
    int ra = -9, rb = -9;
    for (int y = ybeg; y < yend; ++y) {
      const float sy = 0.5f * (float)y - 0.25f;
      const float yf = floorf(sy);
      const float fy = sy - yf;
      const int ys0 = max((int)yf, 0);
      const int ys1 = min((int)yf + 1, PH - 1);
      if (ys0 != ra) {
        if (ys0 == rb) {
          #pragma unroll
          for (int d = 0; d < NDIM; ++d) qa_[d] = qb_[d];
        } else {
          const float* p = peb + (size_t)ys0 * PW;
          #pragma unroll
          for (int d = 0; d < NDIM; ++d)
            qa_[d] = (1.f - fx) * p[d * PH * PW + xs0] + fx * p[d * PH * PW + xs1];
        }
        ra = ys0;
      }
      if (ys1 != rb) {
        if (ys1 == ra) {
          #pragma unroll
          for (int d = 0; d < NDIM; ++d) qb_[d] = qa_[d];
        } else {
          const float* p = peb + (size_t)ys1 * PW;
          #pragma unroll
          for (int d = 0; d < NDIM; ++d)
            qb_[d] = (1.f - fx) * p[d * PH * PW + xs0] + fx * p[d * PH * PW + xs1];
        }
        rb = ys1;
      }
      float d2 = 0.f;
      #pragma unroll
      for (int d = 0; d < NDIM; ++d) {
        const float pv = qa_[d] + fy * (qb_[d] - qa_[d]);
        const float df = e[d] - pv;
        d2 = fmaf(df, df, d2);
      }
      ob[(size_t)y * OW + c] = expf(-d2 * margin);
    }
  }
}

extern "C" void kernel_launch(void* const* d_in, const int* in_sizes, int n_in,
                              void* d_out, int out_size, void* d_ws, size_t ws_size,
                              hipStream_t stream) {
  const float* locations = (const float*)d_in[0];
  const float* box_cls   = (const float*)d_in[1];
  const float* box_reg   = (const float*)d_in[2];
  const float* ctrness   = (const float*)d_in[3];
  const float* pemb      = (const float*)d_in[4];
  const float* pmar      = (const float*)d_in[5];
  const float* pix       = (const float*)d_in[6];
  float* out = (float*)d_out;
  unsigned* ws = (unsigned*)d_ws;

  k_zero_ws<<<dim3(1), dim3(256), 0, stream>>>(ws);
  k_select <<<dim3(2 * SEL_BLOCKS), dim3(256), 0, stream>>>(
      box_cls, ctrness, locations, box_reg, pemb, pmar, ws);
  const int n4 = out_size / 4;  // 14,745,600 f4
  k_fill   <<<dim3(2048), dim3(256), 0, stream>>>((f4*)out, n4);
  k_box    <<<dim3(NBOX), dim3(256), 0, stream>>>(pix, ws, out);
}

// Round 15
// 123.011 us; speedup vs baseline: 1.0514x; 1.0514x over previous
//
#include <hip/hip_runtime.h>
#include <cmath>

// EmbedMaskPostProcessor: top-k select + box decode + embedding-distance masks.
// Output [2,200,384,384] f32 = 236 MB, <1% nonzero -> write-BW bound (~34us floor).
// R15: zero the output with hipMemsetAsync -> dispatches rocclr
// fillBufferAligned, measured at 6.8-7.1 TB/s on this chip every round (our
// hand zero paths never beat ~3.5). R14 taught: separate k_box costs its full
// latency (~20us) when not hidden under a write stream -> 4x its parallelism.
// R4 errata: the "136us memset" rows were poison fills in the WRITE-less
// counter group; in-graph memset nodes are cheap.

namespace {
constexpr int NIMG = 2;
constexpr int NC   = 80;
constexpr int NHW  = 96 * 96;        // 9216
constexpr int NCHW = NC * NHW;       // 737280
constexpr int NDIM = 32;
constexpr int PH = 192, PW = 192;    // pixel_embed spatial
constexpr int OH = 384, OW = 384;    // output mask spatial
constexpr int KTOP = 200;
constexpr int CAP = 4096;            // gathered band candidates per image
constexpr int MCAP = 1024;           // member cap after 27-bit refine
constexpr int LCAP = 512;            // per-block gather buffer
constexpr float PRE_THRESH = 0.05f;
constexpr unsigned KEY_ZERO = 0x80000000u;  // key of +0.0f
constexpr float IMG_MAX = 767.0f;

constexpr int NBOX = NIMG * KTOP;    // 400 boxes; k_box grid = 4x = 1600

constexpr int NF4 = NCHW / 4;        // 184320
constexpr int SEL_BLOCKS = 128;      // selection blocks per image (grid = 256)
constexpr int SEL_STRIDE = SEL_BLOCKS * 256;                    // 32768
constexpr int SEL_ITERS = (NF4 + SEL_STRIDE - 1) / SEL_STRIDE;  // 6

// ws layout (4-byte words); control words on separate 128B lines.
constexpr int WS_HIST1 = 0;                          // [NIMG][2048]
constexpr int WS_CNT   = 4096;                       // [NIMG]
constexpr int WS_BAR   = 4128;                       // [1] sel barrier
constexpr int WS_TICK  = 4160;                       // [NIMG]
constexpr int WS_ZERO_WORDS = 4224;
constexpr int WS_PAIRS = 4224;                       // [NIMG][CAP][2] {key,ref}
constexpr int WS_PARAMS = WS_PAIRS + NIMG * CAP * 2; // [NIMG][KTOP][40]
constexpr int PARAM_WORDS = 40;  // [0]=valid [1..4]=ix0,ix1,iy0,iy1 [5]=margin [8..39]=e

typedef float f4 __attribute__((ext_vector_type(4)));
}

__device__ __forceinline__ unsigned key_of(float f) {
  unsigned u = __float_as_uint(f);
  return (u & 0x80000000u) ? ~u : (u | 0x80000000u);  // monotone: bigger float -> bigger key
}
__device__ __forceinline__ unsigned aget(const unsigned* p) {
  return __hip_atomic_load(p, __ATOMIC_RELAXED, __HIP_MEMORY_SCOPE_AGENT);
}
__device__ __forceinline__ void aput(unsigned* p, unsigned v) {
  __hip_atomic_store(p, v, __ATOMIC_RELAXED, __HIP_MEMORY_SCOPE_AGENT);
}

__global__ __launch_bounds__(256) void k_zero_ws(unsigned* __restrict__ ws) {
  for (int j = threadIdx.x; j < WS_ZERO_WORDS; j += 256) aput(ws + j, 0u);
}

// Fused selection: keygen (keys in regs) -> hist -> spin barrier -> scan ->
// gather (LDS two-phase) -> per-image last-block exact-rank final. (R8-proven.)
__global__ __launch_bounds__(256) void k_select(
    const float* __restrict__ box_cls, const float* __restrict__ ctrness,
    const float* __restrict__ locations, const float* __restrict__ box_reg,
    const float* __restrict__ pemb, const float* __restrict__ pmar,
    unsigned* __restrict__ ws) {
  __shared__ unsigned hist[2048];
  __shared__ unsigned sh_sum[256];
  __shared__ int sh_bk[2];
  __shared__ unsigned loc[LCAP][2];
  __shared__ int lcnt;
  __shared__ unsigned gbase;
  __shared__ int sh_last;
  const int t = threadIdx.x;
  const int n = blockIdx.x >= SEL_BLOCKS;
  const int bi = blockIdx.x - n * SEL_BLOCKS;

  // ---- phase 1: keygen into registers + LDS hist (positives only) ----
  for (int i = t; i < 2048; i += 256) hist[i] = 0;
  __syncthreads();
  const float* cls = box_cls + n * NCHW;
  const float* ctr = ctrness + n * NHW;
  unsigned kk[SEL_ITERS][4];
  #pragma unroll
  for (int s = 0; s < SEL_ITERS; ++s) {
    const int j4 = s * SEL_STRIDE + bi * 256 + t;
    if (j4 < NF4) {
      const int j = j4 * 4;
      const int c = j / NHW;
      const int hw = j - c * NHW;                          // multiple of 4
      const f4 xv = *reinterpret_cast<const f4*>(cls + j);
      const f4 cv = *reinterpret_cast<const f4*>(ctr + hw);
      #pragma unroll
      for (int q = 0; q < 4; ++q) {
        const float sg = 1.0f / (1.0f + expf(-xv[q]));
        float v = -1.0f;
        if (sg > PRE_THRESH) v = sg * (1.0f / (1.0f + expf(-cv[q])));
        const unsigned k = key_of(v);
        kk[s][q] = k;
        if (k > KEY_ZERO) atomicAdd(&hist[k >> 21], 1u);
      }
    } else {
      #pragma unroll
      for (int q = 0; q < 4; ++q) kk[s][q] = 0u;
    }
  }
  __syncthreads();
  {
    unsigned* gh = ws + WS_HIST1 + n * 2048;
    for (int i = t; i < 2048; i += 256) { unsigned v = hist[i]; if (v) atomicAdd(&gh[i], v); }
  }

  // ---- spin barrier across all 256 blocks (alone on device -> harmless) ----
  __syncthreads();
  if (t == 0) {
    atomicAdd(ws + WS_BAR, 1u);
    while (aget(ws + WS_BAR) < (unsigned)(2 * SEL_BLOCKS)) __builtin_amdgcn_s_sleep(2);
  }
  __syncthreads();

  // ---- phase 2: scan global hist for b1/krem ----
  if (t == 0) { sh_bk[0] = -1; sh_bk[1] = KTOP; }
  {
    const unsigned* gh = ws + WS_HIST1 + n * 2048;
    unsigned local = 0;
    for (int j = 0; j < 8; ++j) { unsigned v = aget(gh + t * 8 + j); hist[t * 8 + j] = v; local += v; }
    sh_sum[t] = local;
  }
  __syncthreads();
  {
    unsigned S = 0;
    for (int j = t + 1; j < 256; ++j) S += sh_sum[j];
    int cand_b = -1;
    unsigned cand_above = 0;
    unsigned run = S;
    for (int j = 7; j >= 0; --j) {
      const unsigned cv = hist[t * 8 + j];
      if (cand_b < 0 && run + cv >= (unsigned)KTOP) { cand_b = t * 8 + j; cand_above = run; }
      run += cv;
    }
    if (cand_b >= 0) atomicMax(&sh_bk[0], cand_b);
    __syncthreads();
    if (cand_b >= 0 && cand_b == sh_bk[0]) sh_bk[1] = KTOP - (int)cand_above;
    __syncthreads();
  }
  const unsigned b1 = (unsigned)(sh_bk[0] < 0 ? 0 : sh_bk[0]);
  int krem = sh_bk[1];

  // ---- gather band members from registers -> LDS -> one global reservation ----
  if (t == 0) lcnt = 0;
  __syncthreads();
  #pragma unroll
  for (int s = 0; s < SEL_ITERS; ++s) {
    #pragma unroll
    for (int q = 0; q < 4; ++q) {
      const unsigned k = kk[s][q];
      if ((k >> 21) < b1) continue;
      const int j = (s * SEL_STRIDE + bi * 256 + t) * 4 + q;
      const int c = j / NHW;
      const int hw = j - c * NHW;
      const int p = atomicAdd(&lcnt, 1);
      if (p < LCAP) { loc[p][0] = k; loc[p][1] = (unsigned)(hw * NC + c); }
    }
  }
  __syncthreads();
  const int lc = min(lcnt, LCAP);
  if (t == 0) gbase = atomicAdd(ws + WS_CNT + n, (unsigned)lc);
  __syncthreads();
  for (int i = t; i < lc; i += 256) {
    const unsigned pos = gbase + (unsigned)i;
    if (pos < (unsigned)CAP) {
      aput(&ws[WS_PAIRS + (n * CAP + (int)pos) * 2], loc[i][0]);
      aput(&ws[WS_PAIRS + (n * CAP + (int)pos) * 2 + 1], loc[i][1]);
    }
  }

  // ---- per-image last-block ticket ----
  __syncthreads();
  if (t == 0) {
    const unsigned old = atomicAdd(ws + WS_TICK + n, 1u);
    sh_last = (old == (unsigned)(SEL_BLOCKS - 1)) ? 1 : 0;
  }
  __syncthreads();
  if (!sh_last) return;

  // ---- phase 3 (one block per image): refine to 27-bit prefix, compact
  //      members, exact rank (value desc, index asc = lax.top_k), emit params ----
  __shared__ uint2 P[CAP];               // 32 KiB
  __shared__ unsigned h256[256];
  __shared__ unsigned mKey[MCAP], mRef[MCAP];
  __shared__ int sh_b, sh_t;
  for (int s = t; s < KTOP; s += 256) aput(&ws[WS_PARAMS + (n * KTOP + s) * PARAM_WORDS], 0u);
  const int cnt = min((int)aget(ws + WS_CNT + n), CAP);
  for (int i = t; i < cnt; i += 256) {
    P[i].x = aget(&ws[WS_PAIRS + (n * CAP + i) * 2]);
    P[i].y = aget(&ws[WS_PAIRS + (n * CAP + i) * 2 + 1]);
  }
  __syncthreads();

  unsigned prefix = b1;
  int shift = 21;
  #pragma unroll
  for (int level = 0; level < 2; ++level) {
    const int newshift = shift - 8;
    h256[t] = 0;
    if (t == 0) sh_b = 0;
    __syncthreads();
    for (int i = t; i < cnt; i += 256) {
      const unsigned k = P[i].x;
      if ((k >> shift) == prefix) atomicAdd(&h256[(k >> newshift) & 255u], 1u);
    }
    __syncthreads();
    const unsigned hv = h256[t];
    unsigned S = 0;
    for (int j = t + 1; j < 256; ++j) S += h256[j];
    if (S + hv >= (unsigned)krem) atomicMax(&sh_b, t);
    __syncthreads();
    const int b = sh_b;
    if (t == b) sh_t = krem - (int)S;
    __syncthreads();
    krem = sh_t;
    prefix = (prefix << 8) | (unsigned)b;
    shift = newshift;
    __syncthreads();
  }

  if (t == 0) sh_t = 0;
  __syncthreads();
  for (int i = t; i < cnt; i += 256) {
    const unsigned k = P[i].x;
    if ((k >> 5) >= prefix) {
      const int pos = atomicAdd(&sh_t, 1);
      if (pos < MCAP) { mKey[pos] = k; mRef[pos] = P[i].y; }
    }
  }
  __syncthreads();
  const int m = min(sh_t, MCAP);

  for (int i = t; i < m; i += 256) {
    const unsigned ki = mKey[i], ri = mRef[i];
    int rank = 0;
    for (int j = 0; j < m; ++j) {
      const unsigned kj = mKey[j], rj = mRef[j];
      rank += (kj > ki || (kj == ki && rj < ri)) ? 1 : 0;
    }
    if (rank >= KTOP) continue;
    unsigned* pp = ws + WS_PARAMS + (n * KTOP + rank) * PARAM_WORDS;
    int valid = 0;
    if (ki > KEY_ZERO) {
      const int hw = (int)ri / NC;
      const float lx = locations[2 * hw], ly = locations[2 * hw + 1];
      const float rl = box_reg[(n * 4 + 0) * NHW + hw];
      const float rt = box_reg[(n * 4 + 1) * NHW + hw];
      const float rr = box_reg[(n * 4 + 2) * NHW + hw];
      const float rb = box_reg[(n * 4 + 3) * NHW + hw];
      const float x1 = fminf(fmaxf(lx - rl, 0.f), IMG_MAX);
      const float y1 = fminf(fmaxf(ly - rt, 0.f), IMG_MAX);
      const float x2 = fminf(fmaxf(lx + rr, 0.f), IMG_MAX);
      const float y2 = fminf(fmaxf(ly + rb, 0.f), IMG_MAX);
      const int ix0 = max(0, (int)ceilf(x1 * 0.25f));
      const int ix1 = min(OW - 1, (int)floorf(x2 * 0.25f));
      const int iy0 = max(0, (int)ceilf(y1 * 0.25f));
      const int iy1 = min(OH - 1, (int)floorf(y2 * 0.25f));
      if (ix0 <= ix1 && iy0 <= iy1) {
        valid = 1;
        aput(pp + 1, (unsigned)ix0); aput(pp + 2, (unsigned)ix1);
        aput(pp + 3, (unsigned)iy0); aput(pp + 4, (unsigned)iy1);
        aput(pp + 5, __float_as_uint(pmar[n * NHW + hw]));
        #pragma unroll
        for (int d = 0; d < NDIM; ++d)
          aput(pp + 8 + d, __float_as_uint(pemb[(n * NDIM + d) * NHW + hw]));
      }
    }
    aput(pp + 0, (unsigned)valid);
  }
}

// Box patch: 4 blocks per (n,k) = 1600 blocks; each owns 4 of 16 row-strips.
// Writes ONLY in-box cells over the memset zeros (graph edge = order).
__global__ __launch_bounds__(256) void k_box(const float* __restrict__ pix,
                                             const unsigned* __restrict__ ws,
                                             float* __restrict__ out) {
  const int nk = blockIdx.x >> 2;
  const int quarter = blockIdx.x & 3;
  const int t = threadIdx.x;
  const unsigned* meta = ws + WS_PARAMS + nk * PARAM_WORDS;
  if (meta[0] == 0u) return;
  const int ix0 = (int)meta[1], ix1 = (int)meta[2];
  const int iy0 = (int)meta[3], iy1 = (int)meta[4];
  const float margin = __uint_as_float(meta[5]);
  float e[NDIM];
  {
    const float4* e4 = reinterpret_cast<const float4*>(meta + 8);
    #pragma unroll
    for (int q = 0; q < NDIM / 4; ++q) {
      const float4 v = e4[q];
      e[4 * q + 0] = v.x; e[4 * q + 1] = v.y; e[4 * q + 2] = v.z; e[4 * q + 3] = v.w;
    }
  }
  const int n = nk / KTOP;
  const float* peb = pix + (size_t)n * NDIM * PH * PW;
  float* ob = out + (size_t)nk * (OH * OW);

  const int tx = t & 63;                   // column lane
  const int s16 = quarter * 4 + (t >> 6);  // row strip 0..15
  const int h = iy1 - iy0 + 1;
  const int shh = (h + 15) >> 4;
  const int ybeg = iy0 + s16 * shh;
  const int yend = min(ybeg + shh, iy1 + 1);

  for (int c = ix0 + tx; c <= ix1; c += 64) {
    const float sx = 0.5f * (float)c - 0.25f;
    const float xf = floorf(sx);
    const float fx = sx - xf;
    const int xs0 = max((int)xf, 0);
    const int xs1 = min((int)xf + 1, PW - 1);
    float qa_[NDIM], qb_[NDIM];
    int ra = -9, rb = -9;
    for (int y = ybeg; y < yend; ++y) {
      const float sy = 0.5f * (float)y - 0.25f;
      const float yf = floorf(sy);
      const float fy = sy - yf;
      const int ys0 = max((int)yf, 0);
      const int ys1 = min((int)yf + 1, PH - 1);
      if (ys0 != ra) {
        if (ys0 == rb) {
          #pragma unroll
          for (int d = 0; d < NDIM; ++d) qa_[d] = qb_[d];
        } else {
          const float* p = peb + (size_t)ys0 * PW;
          #pragma unroll
          for (int d = 0; d < NDIM; ++d)
            qa_[d] = (1.f - fx) * p[d * PH * PW + xs0] + fx * p[d * PH * PW + xs1];
        }
        ra = ys0;
      }
      if (ys1 != rb) {
        if (ys1 == ra) {
          #pragma unroll
          for (int d = 0; d < NDIM; ++d) qb_[d] = qa_[d];
        } else {
          const float* p = peb + (size_t)ys1 * PW;
          #pragma unroll
          for (int d = 0; d < NDIM; ++d)
            qb_[d] = (1.f - fx) * p[d * PH * PW + xs0] + fx * p[d * PH * PW + xs1];
        }
        rb = ys1;
      }
      float d2 = 0.f;
      #pragma unroll
      for (int d = 0; d < NDIM; ++d) {
        const float pv = qa_[d] + fy * (qb_[d] - qa_[d]);
        const float df = e[d] - pv;
        d2 = fmaf(df, df, d2);
      }
      ob[(size_t)y * OW + c] = expf(-d2 * margin);
    }
  }
}

extern "C" void kernel_launch(void* const* d_in, const int* in_sizes, int n_in,
                              void* d_out, int out_size, void* d_ws, size_t ws_size,
                              hipStream_t stream) {
  const float* locations = (const float*)d_in[0];
  const float* box_cls   = (const float*)d_in[1];
  const float* box_reg   = (const float*)d_in[2];
  const float* ctrness   = (const float*)d_in[3];
  const float* pemb      = (const float*)d_in[4];
  const float* pmar      = (const float*)d_in[5];
  const float* pix       = (const float*)d_in[6];
  float* out = (float*)d_out;
  unsigned* ws = (unsigned*)d_ws;

  k_zero_ws<<<dim3(1), dim3(256), 0, stream>>>(ws);
  k_select <<<dim3(2 * SEL_BLOCKS), dim3(256), 0, stream>>>(
      box_cls, ctrness, locations, box_reg, pemb, pmar, ws);
  hipMemsetAsync(d_out, 0, (size_t)out_size * sizeof(float), stream);  // rocclr fill @ ~7 TB/s
  k_box    <<<dim3(NBOX * 4), dim3(256), 0, stream>>>(pix, ws, out);
}

// Round 16
// 101.075 us; speedup vs baseline: 1.2796x; 1.2170x over previous
//
#include <hip/hip_runtime.h>
#include <cmath>

// EmbedMaskPostProcessor: top-k select + box decode + embedding-distance masks.
// Output [2,200,384,384] f32 = 236 MB, <1% nonzero.
// R16 = R8 verbatim (best: 100.6us). Evidence-backed floor ~95-100us:
//   - 225MiB output fits L3 and is rewritten every replay -> write stream hits
//     L3-resident dirty lines at ~3.4 TB/s (R15: rocclr's own fill measures
//     1.74 TB/s serialized on this exact buffer vs 7 TB/s on the 944MiB
//     one-shot poison). Zero phase floor ~70us, not 34.
//   - select/write overlap always degrades the stream more than it saves
//     (R9 +4, R10 +273, R11 +99, R12 +9); serial select ~18us.
//   - nt-stores slower than plain (R13 +23); node-split k_box loses its
//     hiding under the zero stream (R14 +29); memset variant (R15 +22).

namespace {
constexpr int NIMG = 2;
constexpr int NC   = 80;
constexpr int NHW  = 96 * 96;        // 9216
constexpr int NCHW = NC * NHW;       // 737280
constexpr int NDIM = 32;
constexpr int PH = 192, PW = 192;    // pixel_embed spatial
constexpr int OH = 384, OW = 384;    // output mask spatial
constexpr int KTOP = 200;
constexpr int CAP = 4096;            // gathered band candidates per image
constexpr int MCAP = 1024;           // member cap after 27-bit refine
constexpr int LCAP = 512;            // per-block gather buffer
constexpr float PRE_THRESH = 0.05f;
constexpr unsigned KEY_ZERO = 0x80000000u;  // key of +0.0f; key > this <=> value > 0
constexpr float IMG_MAX = 767.0f;

constexpr int NBOX = NIMG * KTOP;    // 400 box-compute blocks
constexpr int ZTILES = 6;            // 64-row zero tiles per (n,k)
constexpr int NZB = NBOX * ZTILES;   // 2400 zero blocks

constexpr int NF4 = NCHW / 4;        // 184320 float4 per image
constexpr int SEL_BLOCKS = 128;      // selection blocks per image (grid = 256)
constexpr int SEL_STRIDE = SEL_BLOCKS * 256;                    // 32768
constexpr int SEL_ITERS = (NF4 + SEL_STRIDE - 1) / SEL_STRIDE;  // 6

// ws layout (4-byte words)
constexpr int WS_HIST1  = 0;                         // [NIMG][2048]
constexpr int WS_CNT    = WS_HIST1 + NIMG * 2048;    // [NIMG]
constexpr int WS_BAR    = WS_CNT + NIMG;             // [1] spin barrier
constexpr int WS_TICK   = WS_BAR + 1;                // [NIMG] last-block tickets
constexpr int WS_ZERO_WORDS = WS_TICK + NIMG;        // 4101
constexpr int WS_PAIRS  = 4104;                      // [NIMG][CAP][2] {key,ref}
constexpr int WS_PARAMS = WS_PAIRS + NIMG * CAP * 2; // [NIMG][KTOP][40]
constexpr int PARAM_WORDS = 40;  // [0]=valid [1..4]=ix0,ix1,iy0,iy1 [5]=margin [8..39]=e

typedef float f4 __attribute__((ext_vector_type(4)));
}

__device__ __forceinline__ unsigned key_of(float f) {
  unsigned u = __float_as_uint(f);
  return (u & 0x80000000u) ? ~u : (u | 0x80000000u);  // monotone: bigger float -> bigger key
}

// Zero hist/counters/barrier words (must not rely on cross-call state).
__global__ __launch_bounds__(256) void k_zero_ws(unsigned* __restrict__ ws) {
  for (int j = threadIdx.x; j < WS_ZERO_WORDS; j += 256) ws[j] = 0u;
}

// Fused selection: keygen (keys in regs) -> hist -> spin barrier -> scan ->
// gather (LDS two-phase) -> per-image last-block exact-rank final.
__global__ __launch_bounds__(256) void k_select(
    const float* __restrict__ box_cls, const float* __restrict__ ctrness,
    const float* __restrict__ locations, const float* __restrict__ box_reg,
    const float* __restrict__ pemb, const float* __restrict__ pmar,
    unsigned* __restrict__ ws) {
  __shared__ unsigned hist[2048];          // phase1 hist; phase2 scan scratch
  __shared__ unsigned sh_sum[256];
  __shared__ int sh_bk[2];
  __shared__ unsigned loc[LCAP][2];
  __shared__ int lcnt;
  __shared__ unsigned gbase;
  __shared__ int sh_last;
  const int t = threadIdx.x;
  const int n = blockIdx.x >= SEL_BLOCKS;
  const int bi = blockIdx.x - n * SEL_BLOCKS;

  // ---- phase 1: keygen into registers + LDS hist (positives only) ----
  for (int i = t; i < 2048; i += 256) hist[i] = 0;
  __syncthreads();
  const float* cls = box_cls + n * NCHW;
  const float* ctr = ctrness + n * NHW;
  unsigned kk[SEL_ITERS][4];
  #pragma unroll
  for (int s = 0; s < SEL_ITERS; ++s) {
    const int j4 = s * SEL_STRIDE + bi * 256 + t;
    if (j4 < NF4) {
      const int j = j4 * 4;
      const int c = j / NHW;
      const int hw = j - c * NHW;                          // multiple of 4
      const f4 xv = *reinterpret_cast<const f4*>(cls + j);
      const f4 cv = *reinterpret_cast<const f4*>(ctr + hw);
      #pragma unroll
      for (int q = 0; q < 4; ++q) {
        const float sg = 1.0f / (1.0f + expf(-xv[q]));
        float v = -1.0f;
        if (sg > PRE_THRESH) v = sg * (1.0f / (1.0f + expf(-cv[q])));
        const unsigned k = key_of(v);
        kk[s][q] = k;
        if (k > KEY_ZERO) atomicAdd(&hist[k >> 21], 1u);
      }
    } else {
      #pragma unroll
      for (int q = 0; q < 4; ++q) kk[s][q] = 0u;
    }
  }
  __syncthreads();
  {
    unsigned* gh = ws + WS_HIST1 + n * 2048;
    for (int i = t; i < 2048; i += 256) { unsigned v = hist[i]; if (v) atomicAdd(&gh[i], v); }
  }

  // ---- spin barrier across all 256 blocks (capacity >= grid -> co-resident) ----
  __syncthreads();                       // compiler drains vmcnt before s_barrier
  if (t == 0) {
    atomicAdd(ws + WS_BAR, 1u);
    while (__hip_atomic_load(ws + WS_BAR, __ATOMIC_RELAXED,
                             __HIP_MEMORY_SCOPE_AGENT) < (unsigned)(2 * SEL_BLOCKS)) {
      __builtin_amdgcn_s_sleep(2);
    }
  }
  __syncthreads();

  // ---- phase 2: scan global hist for b1/krem (atomic-written truth at the
  //      device coherence point; no per-XCD dirty copies exist) ----
  if (t == 0) { sh_bk[0] = -1; sh_bk[1] = KTOP; }
  {
    const unsigned* gh = ws + WS_HIST1 + n * 2048;
    unsigned local = 0;
    for (int j = 0; j < 8; ++j) { unsigned v = gh[t * 8 + j]; hist[t * 8 + j] = v; local += v; }
    sh_sum[t] = local;
  }
  __syncthreads();
  {
    unsigned S = 0;
    for (int j = t + 1; j < 256; ++j) S += sh_sum[j];
    int cand_b = -1;
    unsigned cand_above = 0;
    unsigned run = S;
    for (int j = 7; j >= 0; --j) {
      const unsigned cv = hist[t * 8 + j];
      if (cand_b < 0 && run + cv >= (unsigned)KTOP) { cand_b = t * 8 + j; cand_above = run; }
      run += cv;
    }
    if (cand_b >= 0) atomicMax(&sh_bk[0], cand_b);
    __syncthreads();
    if (cand_b >= 0 && cand_b == sh_bk[0]) sh_bk[1] = KTOP - (int)cand_above;
    __syncthreads();
  }
  const unsigned b1 = (unsigned)(sh_bk[0] < 0 ? 0 : sh_bk[0]);
  int krem = sh_bk[1];

  // ---- gather band members from registers -> LDS -> one global reservation ----
  if (t == 0) lcnt = 0;
  __syncthreads();
  #pragma unroll
  for (int s = 0; s < SEL_ITERS; ++s) {
    #pragma unroll
    for (int q = 0; q < 4; ++q) {
      const unsigned k = kk[s][q];
      if ((k >> 21) < b1) continue;
      const int j = (s * SEL_STRIDE + bi * 256 + t) * 4 + q;
      const int c = j / NHW;
      const int hw = j - c * NHW;
      const int p = atomicAdd(&lcnt, 1);
      if (p < LCAP) { loc[p][0] = k; loc[p][1] = (unsigned)(hw * NC + c); }
    }
  }
  __syncthreads();
  const int lc = min(lcnt, LCAP);
  if (t == 0) gbase = atomicAdd(ws + WS_CNT + n, (unsigned)lc);
  __syncthreads();
  for (int i = t; i < lc; i += 256) {
    const unsigned pos = gbase + (unsigned)i;
    if (pos < (unsigned)CAP) {   // AGENT stores: plain stores are not cross-XCD coherent
      __hip_atomic_store(&ws[WS_PAIRS + (n * CAP + (int)pos) * 2], loc[i][0],
                         __ATOMIC_RELAXED, __HIP_MEMORY_SCOPE_AGENT);
      __hip_atomic_store(&ws[WS_PAIRS + (n * CAP + (int)pos) * 2 + 1], loc[i][1],
                         __ATOMIC_RELAXED, __HIP_MEMORY_SCOPE_AGENT);
    }
  }

  // ---- per-image last-block ticket ----
  __syncthreads();                       // drain pair stores before ticket
  if (t == 0) {
    const unsigned old = atomicAdd(ws + WS_TICK + n, 1u);
    sh_last = (old == (unsigned)(SEL_BLOCKS - 1)) ? 1 : 0;
  }
  __syncthreads();
  if (!sh_last) return;

  // ---- phase 3 (one block per image): refine to 27-bit prefix, compact
  //      members, exact rank (value desc, index asc = lax.top_k), emit params ----
  __shared__ uint2 P[CAP];               // 32 KiB
  __shared__ unsigned h256[256];
  __shared__ unsigned mKey[MCAP], mRef[MCAP];
  __shared__ int sh_b, sh_t;
  for (int s = t; s < KTOP; s += 256) ws[WS_PARAMS + (n * KTOP + s) * PARAM_WORDS] = 0u;
  const int cnt = min((int)__hip_atomic_load(ws + WS_CNT + n, __ATOMIC_RELAXED,
                                             __HIP_MEMORY_SCOPE_AGENT), CAP);
  for (int i = t; i < cnt; i += 256) {
    P[i].x = __hip_atomic_load(&ws[WS_PAIRS + (n * CAP + i) * 2],
                               __ATOMIC_RELAXED, __HIP_MEMORY_SCOPE_AGENT);
    P[i].y = __hip_atomic_load(&ws[WS_PAIRS + (n * CAP + i) * 2 + 1],
                               __ATOMIC_RELAXED, __HIP_MEMORY_SCOPE_AGENT);
  }
  __syncthreads();

  unsigned prefix = b1;
  int shift = 21;
  #pragma unroll
  for (int level = 0; level < 2; ++level) {
    const int newshift = shift - 8;
    h256[t] = 0;
    if (t == 0) sh_b = 0;
    __syncthreads();
    for (int i = t; i < cnt; i += 256) {
      const unsigned k = P[i].x;
      if ((k >> shift) == prefix) atomicAdd(&h256[(k >> newshift) & 255u], 1u);
    }
    __syncthreads();
    const unsigned hv = h256[t];
    unsigned S = 0;
    for (int j = t + 1; j < 256; ++j) S += h256[j];
    if (S + hv >= (unsigned)krem) atomicMax(&sh_b, t);
    __syncthreads();
    const int b = sh_b;
    if (t == b) sh_t = krem - (int)S;
    __syncthreads();
    krem = sh_t;
    prefix = (prefix << 8) | (unsigned)b;
    shift = newshift;
    __syncthreads();
  }

  if (t == 0) sh_t = 0;
  __syncthreads();
  for (int i = t; i < cnt; i += 256) {
    const unsigned k = P[i].x;
    if ((k >> 5) >= prefix) {
      const int pos = atomicAdd(&sh_t, 1);
      if (pos < MCAP) { mKey[pos] = k; mRef[pos] = P[i].y; }
    }
  }
  __syncthreads();
  const int m = min(sh_t, MCAP);

  for (int i = t; i < m; i += 256) {
    const unsigned ki = mKey[i], ri = mRef[i];
    int rank = 0;
    for (int j = 0; j < m; ++j) {
      const unsigned kj = mKey[j], rj = mRef[j];
      rank += (kj > ki || (kj == ki && rj < ri)) ? 1 : 0;
    }
    if (rank >= KTOP) continue;
    unsigned* pp = ws + WS_PARAMS + (n * KTOP + rank) * PARAM_WORDS;
    int valid = 0;
    if (ki > KEY_ZERO) {
      const int hw = (int)ri / NC;
      const float lx = locations[2 * hw], ly = locations[2 * hw + 1];
      const float rl = box_reg[(n * 4 + 0) * NHW + hw];
      const float rt = box_reg[(n * 4 + 1) * NHW + hw];
      const float rr = box_reg[(n * 4 + 2) * NHW + hw];
      const float rb = box_reg[(n * 4 + 3) * NHW + hw];
      const float x1 = fminf(fmaxf(lx - rl, 0.f), IMG_MAX);
      const float y1 = fminf(fmaxf(ly - rt, 0.f), IMG_MAX);
      const float x2 = fminf(fmaxf(lx + rr, 0.f), IMG_MAX);
      const float y2 = fminf(fmaxf(ly + rb, 0.f), IMG_MAX);
      const int ix0 = max(0, (int)ceilf(x1 * 0.25f));
      const int ix1 = min(OW - 1, (int)floorf(x2 * 0.25f));
      const int iy0 = max(0, (int)ceilf(y1 * 0.25f));
      const int iy1 = min(OH - 1, (int)floorf(y2 * 0.25f));
      if (ix0 <= ix1 && iy0 <= iy1) {
        valid = 1;
        pp[1] = (unsigned)ix0; pp[2] = (unsigned)ix1;
        pp[3] = (unsigned)iy0; pp[4] = (unsigned)iy1;
        reinterpret_cast<float*>(pp)[5] = pmar[n * NHW + hw];
        float* ep = reinterpret_cast<float*>(pp) + 8;
        #pragma unroll
        for (int d = 0; d < NDIM; ++d) ep[d] = pemb[(n * NDIM + d) * NHW + hw];
      }
    }
    pp[0] = (unsigned)valid;
  }
}

// Fused output kernel, disjoint write ownership. Box blocks FIRST (latency-bound
// gathered reads overlap the zero write stream instead of trailing it).
__global__ __launch_bounds__(256) void k_out(const float* __restrict__ pix,
                                             const unsigned* __restrict__ ws,
                                             float* __restrict__ out) {
  const int bid = blockIdx.x;
  const int t = threadIdx.x;
  if (bid >= NBOX) {
    // ---- zero path ----
    const int zb = bid - NBOX;
    const int nk = zb / ZTILES;
    const int rt = zb - nk * ZTILES;
    const int y0 = rt * 64;
    const unsigned* meta = ws + WS_PARAMS + nk * PARAM_WORDS;
    f4* ob4 = reinterpret_cast<f4*>(out + (size_t)nk * (OH * OW)) + y0 * (OW / 4);
    const f4 z = {0.f, 0.f, 0.f, 0.f};
    int qa = 0, qb = -1, iy0 = 0, iy1 = -1;
    bool overlap = false;
    if (meta[0]) {
      iy0 = (int)meta[3]; iy1 = (int)meta[4];
      if (iy1 >= y0 && iy0 < y0 + 64) {
        overlap = true;
        qa = (int)meta[1] >> 2;
        qb = (int)meta[2] >> 2;
      }
    }
    if (!overlap) {                      // fast path: 24 contiguous f4 stores/thread
      #pragma unroll
      for (int i = 0; i < 24; ++i) ob4[i * 256 + t] = z;
    } else {
      for (int i = 0; i < 24; ++i) {
        const int idx = i * 256 + t;
        const int y = y0 + idx / 96;
        const int q = idx - (idx / 96) * 96;
        if (y >= iy0 && y <= iy1 && q >= qa && q <= qb) continue;  // box block owns
        ob4[idx] = z;
      }
    }
    return;
  }

  // ---- box compute path (padded f4-aligned region; pads written 0) ----
  const int nk = bid;
  const unsigned* meta = ws + WS_PARAMS + nk * PARAM_WORDS;
  if (meta[0] == 0u) return;
  const int ix0 = (int)meta[1], ix1 = (int)meta[2];
  const int iy0 = (int)meta[3], iy1 = (int)meta[4];
  const int xp0 = (ix0 >> 2) << 2;         // padded f4-aligned column range
  const int xp1 = (ix1 >> 2) * 4 + 3;
  const float margin = __uint_as_float(meta[5]);
  float e[NDIM];
  {
    const float4* e4 = reinterpret_cast<const float4*>(meta + 8);
    #pragma unroll
    for (int q = 0; q < NDIM / 4; ++q) {
      const float4 v = e4[q];
      e[4 * q + 0] = v.x; e[4 * q + 1] = v.y; e[4 * q + 2] = v.z; e[4 * q + 3] = v.w;
    }
  }
  const int n = nk / KTOP;
  const float* peb = pix + (size_t)n * NDIM * PH * PW;
  float* ob = out + (size_t)nk * (OH * OW);

  const int tx = t & 63;             // column lane
  const int ts = t >> 6;             // row strip 0..3
  const int h = iy1 - iy0 + 1;
  const int shh = (h + 3) >> 2;
  const int ybeg = iy0 + ts * shh;
  const int yend = min(iy0 + (ts + 1) * shh, iy1 + 1);

  for (int c = xp0 + tx; c <= xp1; c += 64) {
    const bool inx = (c >= ix0) && (c <= ix1);
    const float sx = 0.5f * (float)c - 0.25f;
    const float xf = floorf(sx);
    const float fx = sx - xf;
    const int xs0 = max((int)xf, 0);
    const int xs1 = min((int)xf + 1, PW - 1);
    float qa_[NDIM], qb_[NDIM];
    int ra = -9, rb = -9;
    for (int y = ybeg; y < yend; ++y) {
      float val = 0.f;
      if (inx) {
        const float sy = 0.5f * (float)y - 0.25f;
        const float yf = floorf(sy);
        const float fy = sy - yf;
        const int ys0 = max((int)yf, 0);
        const int ys1 = min((int)yf + 1, PH - 1);
        if (ys0 != ra) {
          if (ys0 == rb) {
            #pragma unroll
            for (int d = 0; d < NDIM; ++d) qa_[d] = qb_[d];
          } else {
            const float* p = peb + (size_t)ys0 * PW;
            #pragma unroll
            for (int d = 0; d < NDIM; ++d)
              qa_[d] = (1.f - fx) * p[d * PH * PW + xs0] + fx * p[d * PH * PW + xs1];
          }
          ra = ys0;
        }
        if (ys1 != rb) {
          if (ys1 == ra) {
            #pragma unroll
            for (int d = 0; d < NDIM; ++d) qb_[d] = qa_[d];
          } else {
            const float* p = peb + (size_t)ys1 * PW;
            #pragma unroll
            for (int d = 0; d < NDIM; ++d)
              qb_[d] = (1.f - fx) * p[d * PH * PW + xs0] + fx * p[d * PH * PW + xs1];
          }
          rb = ys1;
        }
        float d2 = 0.f;
        #pragma unroll
        for (int d = 0; d < NDIM; ++d) {
          const float pv = qa_[d] + fy * (qb_[d] - qa_[d]);
          const float df = e[d] - pv;
          d2 = fmaf(df, df, d2);
        }
        val = expf(-d2 * margin);
      }
      ob[(size_t)y * OW + c] = val;
    }
  }
}

extern "C" void kernel_launch(void* const* d_in, const int* in_sizes, int n_in,
                              void* d_out, int out_size, void* d_ws, size_t ws_size,
                              hipStream_t stream) {
  const float* locations = (const float*)d_in[0];
  const float* box_cls   = (const float*)d_in[1];
  const float* box_reg   = (const float*)d_in[2];
  const float* ctrness   = (const float*)d_in[3];
  const float* pemb      = (const float*)d_in[4];
  const float* pmar      = (const float*)d_in[5];
  const float* pix       = (const float*)d_in[6];
  float* out = (float*)d_out;
  unsigned* ws = (unsigned*)d_ws;

  k_zero_ws<<<dim3(1), dim3(256), 0, stream>>>(ws);
  k_select <<<dim3(2 * SEL_BLOCKS), dim3(256), 0, stream>>>(
      box_cls, ctrness, locations, box_reg, pemb, pmar, ws);
  k_out    <<<dim3(NBOX + NZB), dim3(256), 0, stream>>>(pix, ws, out);
}